// Round 7
// baseline (401.399 us; speedup 1.0000x reference)
//
#include <hip/hip_runtime.h>
#include <hip/hip_bf16.h>

typedef unsigned short u16;
typedef __bf16 bf16x8 __attribute__((ext_vector_type(8)));
typedef u16 u16x8 __attribute__((ext_vector_type(8)));
typedef float f32x4 __attribute__((ext_vector_type(4)));

__device__ __forceinline__ float bf2f(u16 u) {
    return __uint_as_float(((unsigned)u) << 16);
}
__device__ __forceinline__ u16 f2bf(float f) {
    unsigned u = __float_as_uint(f);
    unsigned r = (u + 0x7fffu + ((u >> 16) & 1u)) >> 16;
    return (u16)r;
}

// async global->LDS, 16B per lane. dst is wave-uniform base; HW adds lane*16.
__device__ __forceinline__ void gl_lds16(const u16* g, u16* l) {
    __builtin_amdgcn_global_load_lds(
        (const __attribute__((address_space(1))) void*)g,
        (__attribute__((address_space(3))) void*)l, 16, 0, 0);
}

// ---------------- fused prep: x f32->bf16 convert + 3 weight transposes ----------------
// blocks [0,10280): convert; [10280,10472): Wv; [10472,10664): Wa; [10664,10728): Wo
__global__ __launch_bounds__(256) void prep(const float* __restrict__ x,
                                            const float* __restrict__ Wv,
                                            const float* __restrict__ Wa,
                                            const float* __restrict__ Wo,
                                            u16* __restrict__ xb,
                                            u16* __restrict__ WvT,
                                            u16* __restrict__ WaT,
                                            u16* __restrict__ WoT) {
    __shared__ float tile[64][65];
    int blk = blockIdx.x;
    if (blk < 10280) {
        int i = (blk * 256 + threadIdx.x) * 8;
        float4 a = *(const float4*)&x[i];
        float4 b = *(const float4*)&x[i + 4];
        u16x8 o;
        o[0] = f2bf(a.x); o[1] = f2bf(a.y); o[2] = f2bf(a.z); o[3] = f2bf(a.w);
        o[4] = f2bf(b.x); o[5] = f2bf(b.y); o[6] = f2bf(b.z); o[7] = f2bf(b.w);
        *(u16x8*)&xb[i] = o;
        return;
    }
    blk -= 10280;
    const float* W; u16* WT; int N;
    if (blk < 192)      { W = Wv; WT = WvT; N = 1536; }
    else if (blk < 384) { W = Wa; WT = WaT; N = 1536; blk -= 192; }
    else                { W = Wo; WT = WoT; N = 512;  blk -= 384; }
    const int K = 512;
    const int nt = N >> 6;
    const int k0 = (blk / nt) << 6;
    const int n0 = (blk % nt) << 6;
    for (int i = threadIdx.x; i < 4096; i += 256) {
        int r = i >> 6, c = i & 63;
        tile[r][c] = W[(size_t)(k0 + r) * N + n0 + c];
    }
    __syncthreads();
    for (int i = threadIdx.x; i < 4096; i += 256) {
        int r = i >> 6, c = i & 63;
        WT[(size_t)(n0 + r) * K + k0 + c] = f2bf(tile[c][r]);
    }
}

// ---------------- generic MFMA GEMM (used for A-projection and out-proj) ----------
// MODE 0: row r -> r (clamp).  MODE 2: r -> r*257 (clamp). OUTF: float out (+bias).
template <int MODE, int OUTF>
__global__ __launch_bounds__(256) void gemm_k(const u16* __restrict__ A,
                                              const u16* __restrict__ Bt,
                                              void* __restrict__ Cv,
                                              const float* __restrict__ bias,
                                              int M, int N, int K) {
    __shared__ u16 As[128][64];
    __shared__ u16 Bs[128][64];
    const int t = threadIdx.x;
    const int bn0 = blockIdx.x * 128;
    const int bm0 = blockIdx.y * 128;
    const int wave = t >> 6, lane = t & 63;
    const int wm = (wave >> 1) * 64, wn = (wave & 1) * 64;
    const int lr = lane & 15, lh = lane >> 4;
    const int srow = wave * 8 + (lane >> 3);
    const int scol = (lane & 7) * 8;

    f32x4 acc[4][4] = {};

    for (int kt = 0; kt < K; kt += 64) {
        __syncthreads();
#pragma unroll
        for (int i = 0; i < 4; i++) {
            int row = i * 32 + srow;
            int r = bm0 + row;
            long g;
            if (MODE == 0) g = (r < M) ? (long)r : 0l;
            else           g = (r < M) ? (long)r * 257 : 0l;
            gl_lds16(&A[g * K + kt + scol], &As[0][0] + i * 2048 + wave * 512);
            long nr = bn0 + row;
            gl_lds16(&Bt[nr * K + kt + scol], &Bs[0][0] + i * 2048 + wave * 512);
        }
        __syncthreads();
#pragma unroll
        for (int kk = 0; kk < 2; kk++) {
            bf16x8 af[4], bfr[4];
#pragma unroll
            for (int mi = 0; mi < 4; mi++)
                af[mi] = *(const bf16x8*)&As[wm + mi * 16 + lr][kk * 32 + lh * 8];
#pragma unroll
            for (int ni = 0; ni < 4; ni++)
                bfr[ni] = *(const bf16x8*)&Bs[wn + ni * 16 + lr][kk * 32 + lh * 8];
#pragma unroll
            for (int mi = 0; mi < 4; mi++)
#pragma unroll
                for (int ni = 0; ni < 4; ni++)
                    acc[mi][ni] = __builtin_amdgcn_mfma_f32_16x16x32_bf16(
                        af[mi], bfr[ni], acc[mi][ni], 0, 0, 0);
        }
    }

#pragma unroll
    for (int mi = 0; mi < 4; mi++)
#pragma unroll
        for (int ni = 0; ni < 4; ni++)
#pragma unroll
            for (int r2 = 0; r2 < 4; r2++) {
                int m = bm0 + wm + mi * 16 + lh * 4 + r2;
                if (m < M) {
                    int nc = bn0 + wn + ni * 16 + lr;
                    float v = acc[mi][ni][r2];
                    if (OUTF) ((float*)Cv)[(size_t)m * N + nc] = v + bias[nc];
                    else      ((u16*)Cv)[(size_t)m * N + nc] = f2bf(v);
                }
            }
}

// ---------------- fused V-QKV GEMM with attention epilogues ----------------
// C-tile = xb_V[40960][512] @ WvT[1536][512]^T. Grid (12, 320).
// n-section: 0=Q (va-attention fused, writes cat V-rows), 1=K (scores -> pglob),
// 2=V (writes compact vv[40960][512]).
// Each block = one bt (batch-token); each wave's 64-col span = one head.
__global__ __launch_bounds__(256, 4) void gemm_qkv(const u16* __restrict__ A,
                                                   const u16* __restrict__ Bt,
                                                   const u16* __restrict__ aqkv,
                                                   const float* __restrict__ mask,
                                                   u16* __restrict__ vv,
                                                   float* __restrict__ pglob,
                                                   u16* __restrict__ cat) {
    __shared__ u16 As[128][64];
    __shared__ u16 Bs[128][64];
    const int t = threadIdx.x;
    const int bn0 = blockIdx.x * 128;
    const int bm0 = blockIdx.y * 128;
    const int wave = t >> 6, lane = t & 63;
    const int wm = (wave >> 1) * 64, wn = (wave & 1) * 64;
    const int lr = lane & 15, lh = lane >> 4;
    const int srow = wave * 8 + (lane >> 3);
    const int scol = (lane & 7) * 8;

    f32x4 acc[4][4] = {};

    for (int kt = 0; kt < 512; kt += 64) {
        __syncthreads();
#pragma unroll
        for (int i = 0; i < 4; i++) {
            int row = i * 32 + srow;
            int r = bm0 + row;
            long g = (long)(r >> 8) * 257 + (r & 255) + 1;   // V rows of x
            gl_lds16(&A[g * 512 + kt + scol], &As[0][0] + i * 2048 + wave * 512);
            long nr = bn0 + row;
            gl_lds16(&Bt[nr * 512 + kt + scol], &Bs[0][0] + i * 2048 + wave * 512);
        }
        __syncthreads();
#pragma unroll
        for (int kk = 0; kk < 2; kk++) {
            bf16x8 af[4], bfr[4];
#pragma unroll
            for (int mi = 0; mi < 4; mi++)
                af[mi] = *(const bf16x8*)&As[wm + mi * 16 + lr][kk * 32 + lh * 8];
#pragma unroll
            for (int ni = 0; ni < 4; ni++)
                bfr[ni] = *(const bf16x8*)&Bs[wn + ni * 16 + lr][kk * 32 + lh * 8];
#pragma unroll
            for (int mi = 0; mi < 4; mi++)
#pragma unroll
                for (int ni = 0; ni < 4; ni++)
                    acc[mi][ni] = __builtin_amdgcn_mfma_f32_16x16x32_bf16(
                        af[mi], bfr[ni], acc[mi][ni], 0, 0, 0);
        }
    }

    const int bt   = bm0 >> 8;                    // 0..159, uniform per block
    const int sec  = bn0 >> 9;                    // 0=Q, 1=K, 2=V
    const int head = ((bn0 & 511) + wn) >> 6;     // 0..7, uniform per wave
    const int b5   = bt / 5, t5 = bt - b5 * 5;
    const int jb   = (bm0 & 255) + wm;            // wave row base j (0..192)

    if (sec == 2) {
        const int nc0 = (bn0 & 511) + wn;
#pragma unroll
        for (int mi = 0; mi < 4; mi++)
#pragma unroll
            for (int ni = 0; ni < 4; ni++)
#pragma unroll
                for (int r2 = 0; r2 < 4; r2++) {
                    int r = bt * 256 + jb + mi * 16 + lh * 4 + r2;
                    vv[(size_t)r * 512 + nc0 + ni * 16 + lr] = f2bf(acc[mi][ni][r2]);
                }
        return;
    }

    // per-lane attention operand columns d = ni*16 + lr of this head
    const int aoff = (sec == 1) ? 0 : 512;        // K-epi: qa; Q-epi: ka
    float wA[5][4];
#pragma unroll
    for (int q = 0; q < 5; q++)
#pragma unroll
        for (int ni = 0; ni < 4; ni++)
            wA[q][ni] = bf2f(aqkv[(size_t)(b5 * 5 + q) * 1536 + aoff + head * 64 + ni * 16 + lr]);

    if (sec == 1) {
        // scores: pglob[(b*8+head)*5+q][t5*256 + j] = 0.125 * dot(kv_row, qa_q)
#pragma unroll
        for (int mi = 0; mi < 4; mi++) {
            f32x4 sc[5];
#pragma unroll
            for (int q = 0; q < 5; q++) {
                sc[q] = acc[mi][0] * wA[q][0];
#pragma unroll
                for (int ni = 1; ni < 4; ni++) sc[q] += acc[mi][ni] * wA[q][ni];
            }
#pragma unroll
            for (int off = 1; off < 16; off <<= 1)
#pragma unroll
                for (int q = 0; q < 5; q++)
#pragma unroll
                    for (int c = 0; c < 4; c++)
                        sc[q][c] += __shfl_xor(sc[q][c], off);
            if (lr < 5) {
                const int q = lr;
                const int j0 = jb + mi * 16 + lh * 4;
                f32x4 v = sc[q] * 0.125f;
                *(f32x4*)&pglob[((size_t)(b5 * 8 + head) * 5 + q) * 1280 + t5 * 256 + j0] = v;
            }
        }
    } else {
        // va attention: per row, 5 scores vs ka, mask+scale, softmax5, @ va -> cat
        float wV[5][4];
#pragma unroll
        for (int q = 0; q < 5; q++)
#pragma unroll
            for (int ni = 0; ni < 4; ni++)
                wV[q][ni] = bf2f(aqkv[(size_t)(b5 * 5 + q) * 1536 + 1024 + head * 64 + ni * 16 + lr]);
#pragma unroll
        for (int mi = 0; mi < 4; mi++) {
            f32x4 sc[5];
#pragma unroll
            for (int q = 0; q < 5; q++) {
                sc[q] = acc[mi][0] * wA[q][0];
#pragma unroll
                for (int ni = 1; ni < 4; ni++) sc[q] += acc[mi][ni] * wA[q][ni];
            }
#pragma unroll
            for (int off = 1; off < 16; off <<= 1)
#pragma unroll
                for (int q = 0; q < 5; q++)
#pragma unroll
                    for (int c = 0; c < 4; c++)
                        sc[q][c] += __shfl_xor(sc[q][c], off);
            const int j0 = jb + mi * 16 + lh * 4;
            f32x4 mv;
#pragma unroll
            for (int c = 0; c < 4; c++) mv[c] = mask[bt * 256 + j0 + c] * 0.125f;
#pragma unroll
            for (int q = 0; q < 5; q++) sc[q] *= mv;
            f32x4 mx = sc[0];
#pragma unroll
            for (int q = 1; q < 5; q++)
#pragma unroll
                for (int c = 0; c < 4; c++) mx[c] = fmaxf(mx[c], sc[q][c]);
            f32x4 se = {};
#pragma unroll
            for (int q = 0; q < 5; q++) {
#pragma unroll
                for (int c = 0; c < 4; c++) sc[q][c] = __expf(sc[q][c] - mx[c]);
                se += sc[q];
            }
            f32x4 inv;
#pragma unroll
            for (int c = 0; c < 4; c++) inv[c] = 1.f / se[c];
#pragma unroll
            for (int ni = 0; ni < 4; ni++) {
                f32x4 o = sc[0] * wV[0][ni];
#pragma unroll
                for (int q = 1; q < 5; q++) o += sc[q] * wV[q][ni];
                o *= inv;
#pragma unroll
                for (int r2 = 0; r2 < 4; r2++) {
                    size_t g = (size_t)bt * 257 + 1 + j0 + r2;
                    cat[g * 512 + head * 64 + ni * 16 + lr] = f2bf(o[r2]);
                }
            }
        }
    }
}

// --- softmax in place over pglob rows. wave-per-row; grid 320 x 256 thr ---
__global__ __launch_bounds__(256) void av_softmax(float* __restrict__ pglob) {
    const int wave = threadIdx.x >> 6, lane = threadIdx.x & 63;
    const int rid = blockIdx.x * 4 + wave;
    float* row = pglob + (size_t)rid * 1280;
    float v[20];
    float mx = -3.4e38f;
#pragma unroll
    for (int i = 0; i < 20; i++) {
        v[i] = row[lane + i * 64];
        mx = fmaxf(mx, v[i]);
    }
#pragma unroll
    for (int off = 32; off > 0; off >>= 1) mx = fmaxf(mx, __shfl_xor(mx, off));
    float sum = 0.f;
#pragma unroll
    for (int i = 0; i < 20; i++) {
        v[i] = __expf(v[i] - mx);
        sum += v[i];
    }
#pragma unroll
    for (int off = 32; off > 0; off >>= 1) sum += __shfl_xor(sum, off);
    const float inv = 1.f / sum;
#pragma unroll
    for (int i = 0; i < 20; i++) row[lane + i * 64] = v[i] * inv;
}

// --- PV partials. grid 2048 = (bh)(256) x jc(8); 320 thr, wave=q, lane=d ---
__global__ __launch_bounds__(320) void av_pv(const u16* __restrict__ vv,
                                             const float* __restrict__ pglob,
                                             float* __restrict__ avpart) {
    __shared__ float pl[5][5][32];   // [q][t5][jj]
    const int blk = blockIdx.x;
    const int jc = blk & 7;
    const int bh = blk >> 3;
    const int bi = bh >> 3, hd = bh & 7;
    const int t = threadIdx.x;
    for (int ii = t; ii < 800; ii += 320) {
        int q = ii / 160, rem = ii - q * 160;
        int tt = rem >> 5, jj = rem & 31;
        pl[q][tt][jj] = pglob[((size_t)bh * 5 + q) * 1280 + tt * 256 + jc * 32 + jj];
    }
    __syncthreads();
    const int wave = t >> 6, lane = t & 63;   // wave = q
    float acc = 0.f;
    const int j0 = jc * 32;
    for (int jj = 0; jj < 32; jj++) {
#pragma unroll
        for (int t5 = 0; t5 < 5; t5++) {
            float v = bf2f(vv[((size_t)((bi * 5 + t5) * 256 + j0 + jj)) * 512 + hd * 64 + lane]);
            acc += pl[wave][t5][jj] * v;
        }
    }
    avpart[((size_t)jc * 1280 + (size_t)bh * 5 + wave) * 64 + lane] = acc;
}

// --- reduce partials -> cat A-rows. grid 320 x 256 thr ---
__global__ __launch_bounds__(256) void av_write(const float* __restrict__ avpart,
                                                u16* __restrict__ cat) {
    const int idx = blockIdx.x * 256 + threadIdx.x;
    const int d = idx & 63;
    const int r = idx >> 6;                   // 0..1279 = bh*5+q
    const int q = r % 5, bh = r / 5;
    const int bi = bh >> 3, hd = bh & 7;
    float s = 0.f;
#pragma unroll
    for (int jc = 0; jc < 8; jc++) s += avpart[((size_t)jc * 1280 + r) * 64 + d];
    cat[(size_t)((bi * 5 + q) * 257) * 512 + hd * 64 + d] = f2bf(s);
}

extern "C" void kernel_launch(void* const* d_in, const int* in_sizes, int n_in,
                              void* d_out, int out_size, void* d_ws, size_t ws_size,
                              hipStream_t stream) {
    const float* x    = (const float*)d_in[0];  // (160,257,512) f32
    const float* mask = (const float*)d_in[1];  // (160,256) f32
    const float* Wv   = (const float*)d_in[2];  // (512,1536) f32
    const float* Wa   = (const float*)d_in[3];  // (512,1536) f32
    const float* Wo   = (const float*)d_in[4];  // (512,512) f32
    const float* bo   = (const float*)d_in[5];  // (512,) f32
    float* out = (float*)d_out;

    char* ws = (char*)d_ws;
    u16*   xb     = (u16*)(ws);                   // 42,106,880 B
    u16*   WvT    = (u16*)(ws + 42106880);        //  1,572,864 B
    u16*   WaT    = (u16*)(ws + 43679744);        //  1,572,864 B
    u16*   WoT    = (u16*)(ws + 45252608);        //    524,288 B
    u16*   aqkv   = (u16*)(ws + 45776896);        //    491,520 B
    u16*   vv     = (u16*)(ws + 46268416);        // 41,943,040 B
    u16*   cat    = (u16*)(ws + 88211456);        // 42,106,880 B
    float* pglob  = (float*)(ws + 130318336);     //  6,553,600 B
    float* avpart = (float*)(ws + 136871936);     //  2,621,440 B -> ~139.5 MB

    prep<<<dim3(10728), 256, 0, stream>>>(x, Wv, Wa, Wo, xb, WvT, WaT, WoT);

    // a_qkv = A @ Wa_qkv (must precede gemm_qkv: its epilogues read aqkv)
    gemm_k<2, 0><<<dim3(12, 2), 256, 0, stream>>>(xb, WaT, aqkv, nullptr, 160, 1536, 512);

    // V-QKV GEMM with fused attention epilogues
    gemm_qkv<<<dim3(12, 320), 256, 0, stream>>>(xb, WvT, aqkv, mask, vv, pglob, cat);

    av_softmax<<<dim3(320), 256, 0, stream>>>(pglob);
    av_pv<<<dim3(2048), 320, 0, stream>>>(vv, pglob, avpart);
    av_write<<<dim3(320), 256, 0, stream>>>(avpart, cat);

    // out = cat @ Wo + bo   (float out)
    gemm_k<0, 1><<<dim3(4, 322), 256, 0, stream>>>(cat, WoT, out, bo, 41120, 512, 512);
}

// Round 8
// 360.324 us; speedup vs baseline: 1.1140x; 1.1140x over previous
//
#include <hip/hip_runtime.h>
#include <hip/hip_bf16.h>

typedef unsigned short u16;
typedef __bf16 bf16x8 __attribute__((ext_vector_type(8)));
typedef u16 u16x8 __attribute__((ext_vector_type(8)));
typedef float f32x4 __attribute__((ext_vector_type(4)));

__device__ __forceinline__ float bf2f(u16 u) {
    return __uint_as_float(((unsigned)u) << 16);
}
__device__ __forceinline__ u16 f2bf(float f) {
    unsigned u = __float_as_uint(f);
    unsigned r = (u + 0x7fffu + ((u >> 16) & 1u)) >> 16;
    return (u16)r;
}

// async global->LDS, 16B per lane. dst is wave-uniform base; HW adds lane*16.
__device__ __forceinline__ void gl_lds16(const u16* g, u16* l) {
    __builtin_amdgcn_global_load_lds(
        (const __attribute__((address_space(1))) void*)g,
        (__attribute__((address_space(3))) void*)l, 16, 0, 0);
}

// ---------------- fused prep: x f32->bf16 convert + 3 weight transposes ----------------
// blocks [0,10280): convert; [10280,10472): Wv; [10472,10664): Wa; [10664,10728): Wo
__global__ __launch_bounds__(256) void prep(const float* __restrict__ x,
                                            const float* __restrict__ Wv,
                                            const float* __restrict__ Wa,
                                            const float* __restrict__ Wo,
                                            u16* __restrict__ xb,
                                            u16* __restrict__ WvT,
                                            u16* __restrict__ WaT,
                                            u16* __restrict__ WoT) {
    __shared__ float tile[64][65];
    int blk = blockIdx.x;
    if (blk < 10280) {
        int i = (blk * 256 + threadIdx.x) * 8;
        float4 a = *(const float4*)&x[i];
        float4 b = *(const float4*)&x[i + 4];
        u16x8 o;
        o[0] = f2bf(a.x); o[1] = f2bf(a.y); o[2] = f2bf(a.z); o[3] = f2bf(a.w);
        o[4] = f2bf(b.x); o[5] = f2bf(b.y); o[6] = f2bf(b.z); o[7] = f2bf(b.w);
        *(u16x8*)&xb[i] = o;
        return;
    }
    blk -= 10280;
    const float* W; u16* WT; int N;
    if (blk < 192)      { W = Wv; WT = WvT; N = 1536; }
    else if (blk < 384) { W = Wa; WT = WaT; N = 1536; blk -= 192; }
    else                { W = Wo; WT = WoT; N = 512;  blk -= 384; }
    const int K = 512;
    const int nt = N >> 6;
    const int k0 = (blk / nt) << 6;
    const int n0 = (blk % nt) << 6;
    for (int i = threadIdx.x; i < 4096; i += 256) {
        int r = i >> 6, c = i & 63;
        tile[r][c] = W[(size_t)(k0 + r) * N + n0 + c];
    }
    __syncthreads();
    for (int i = threadIdx.x; i < 4096; i += 256) {
        int r = i >> 6, c = i & 63;
        WT[(size_t)(n0 + r) * K + k0 + c] = f2bf(tile[c][r]);
    }
}

// ---------------- generic MFMA GEMM (used for A-projection and out-proj) ----------
// MODE 0: row r -> r (clamp).  MODE 2: r -> r*257 (clamp). OUTF: float out (+bias).
template <int MODE, int OUTF>
__global__ __launch_bounds__(256) void gemm_k(const u16* __restrict__ A,
                                              const u16* __restrict__ Bt,
                                              void* __restrict__ Cv,
                                              const float* __restrict__ bias,
                                              int M, int N, int K) {
    __shared__ u16 As[128][64];
    __shared__ u16 Bs[128][64];
    const int t = threadIdx.x;
    const int bn0 = blockIdx.x * 128;
    const int bm0 = blockIdx.y * 128;
    const int wave = t >> 6, lane = t & 63;
    const int wm = (wave >> 1) * 64, wn = (wave & 1) * 64;
    const int lr = lane & 15, lh = lane >> 4;
    const int srow = wave * 8 + (lane >> 3);
    const int scol = (lane & 7) * 8;

    f32x4 acc[4][4] = {};

    for (int kt = 0; kt < K; kt += 64) {
        __syncthreads();
#pragma unroll
        for (int i = 0; i < 4; i++) {
            int row = i * 32 + srow;
            int r = bm0 + row;
            long g;
            if (MODE == 0) g = (r < M) ? (long)r : 0l;
            else           g = (r < M) ? (long)r * 257 : 0l;
            gl_lds16(&A[g * K + kt + scol], &As[0][0] + i * 2048 + wave * 512);
            long nr = bn0 + row;
            gl_lds16(&Bt[nr * K + kt + scol], &Bs[0][0] + i * 2048 + wave * 512);
        }
        __syncthreads();
#pragma unroll
        for (int kk = 0; kk < 2; kk++) {
            bf16x8 af[4], bfr[4];
#pragma unroll
            for (int mi = 0; mi < 4; mi++)
                af[mi] = *(const bf16x8*)&As[wm + mi * 16 + lr][kk * 32 + lh * 8];
#pragma unroll
            for (int ni = 0; ni < 4; ni++)
                bfr[ni] = *(const bf16x8*)&Bs[wn + ni * 16 + lr][kk * 32 + lh * 8];
#pragma unroll
            for (int mi = 0; mi < 4; mi++)
#pragma unroll
                for (int ni = 0; ni < 4; ni++)
                    acc[mi][ni] = __builtin_amdgcn_mfma_f32_16x16x32_bf16(
                        af[mi], bfr[ni], acc[mi][ni], 0, 0, 0);
        }
    }

#pragma unroll
    for (int mi = 0; mi < 4; mi++)
#pragma unroll
        for (int ni = 0; ni < 4; ni++)
#pragma unroll
            for (int r2 = 0; r2 < 4; r2++) {
                int m = bm0 + wm + mi * 16 + lh * 4 + r2;
                if (m < M) {
                    int nc = bn0 + wn + ni * 16 + lr;
                    float v = acc[mi][ni][r2];
                    if (OUTF) ((float*)Cv)[(size_t)m * N + nc] = v + bias[nc];
                    else      ((u16*)Cv)[(size_t)m * N + nc] = f2bf(v);
                }
            }
}

// ---------------- fused V-QKV GEMM with attention epilogues ----------------
// C-tile = xb_V[40960][512] @ WvT[1536][512]^T. Grid (12, 320).
// n-section: 0=Q (va-attention fused, writes cat V-rows), 1=K (scores -> pglob),
// 2=V (writes compact vv[40960][512]).
// Each block = one bt (batch-token); each wave's 64-col span = one head.
// NOTE: no occupancy cap — round-7's (256,4) forced 128-reg budget and the
// epilogue spilled to scratch (WRITE_SIZE 123->524 MB, 2.5x slower).
__global__ __launch_bounds__(256) void gemm_qkv(const u16* __restrict__ A,
                                                const u16* __restrict__ Bt,
                                                const u16* __restrict__ aqkv,
                                                const float* __restrict__ mask,
                                                u16* __restrict__ vv,
                                                float* __restrict__ pglob,
                                                u16* __restrict__ cat) {
    __shared__ u16 As[128][64];
    __shared__ u16 Bs[128][64];
    const int t = threadIdx.x;
    const int bn0 = blockIdx.x * 128;
    const int bm0 = blockIdx.y * 128;
    const int wave = t >> 6, lane = t & 63;
    const int wm = (wave >> 1) * 64, wn = (wave & 1) * 64;
    const int lr = lane & 15, lh = lane >> 4;
    const int srow = wave * 8 + (lane >> 3);
    const int scol = (lane & 7) * 8;

    f32x4 acc[4][4] = {};

    for (int kt = 0; kt < 512; kt += 64) {
        __syncthreads();
#pragma unroll
        for (int i = 0; i < 4; i++) {
            int row = i * 32 + srow;
            int r = bm0 + row;
            long g = (long)(r >> 8) * 257 + (r & 255) + 1;   // V rows of x
            gl_lds16(&A[g * 512 + kt + scol], &As[0][0] + i * 2048 + wave * 512);
            long nr = bn0 + row;
            gl_lds16(&Bt[nr * 512 + kt + scol], &Bs[0][0] + i * 2048 + wave * 512);
        }
        __syncthreads();
#pragma unroll
        for (int kk = 0; kk < 2; kk++) {
            bf16x8 af[4], bfr[4];
#pragma unroll
            for (int mi = 0; mi < 4; mi++)
                af[mi] = *(const bf16x8*)&As[wm + mi * 16 + lr][kk * 32 + lh * 8];
#pragma unroll
            for (int ni = 0; ni < 4; ni++)
                bfr[ni] = *(const bf16x8*)&Bs[wn + ni * 16 + lr][kk * 32 + lh * 8];
#pragma unroll
            for (int mi = 0; mi < 4; mi++)
#pragma unroll
                for (int ni = 0; ni < 4; ni++)
                    acc[mi][ni] = __builtin_amdgcn_mfma_f32_16x16x32_bf16(
                        af[mi], bfr[ni], acc[mi][ni], 0, 0, 0);
        }
    }

    const int bt   = bm0 >> 8;                    // 0..159, uniform per block
    const int sec  = bn0 >> 9;                    // 0=Q, 1=K, 2=V
    const int head = ((bn0 & 511) + wn) >> 6;     // 0..7, uniform per wave
    const int b5   = bt / 5, t5 = bt - b5 * 5;
    const int jb   = (bm0 & 255) + wm;            // wave row base j (0..192)

    if (sec == 2) {
        const int nc0 = (bn0 & 511) + wn;
#pragma unroll
        for (int mi = 0; mi < 4; mi++)
#pragma unroll
            for (int ni = 0; ni < 4; ni++)
#pragma unroll
                for (int r2 = 0; r2 < 4; r2++) {
                    int r = bt * 256 + jb + mi * 16 + lh * 4 + r2;
                    vv[(size_t)r * 512 + nc0 + ni * 16 + lr] = f2bf(acc[mi][ni][r2]);
                }
        return;
    }

    // per-lane attention operand columns d = ni*16 + lr of this head
    const int aoff = (sec == 1) ? 0 : 512;        // K-epi: qa; Q-epi: ka
    float wA[5][4];
#pragma unroll
    for (int q = 0; q < 5; q++)
#pragma unroll
        for (int ni = 0; ni < 4; ni++)
            wA[q][ni] = bf2f(aqkv[(size_t)(b5 * 5 + q) * 1536 + aoff + head * 64 + ni * 16 + lr]);

    if (sec == 1) {
        // scores: pglob[(b*8+head)*5+q][t5*256 + j] = 0.125 * dot(kv_row, qa_q)
#pragma unroll
        for (int mi = 0; mi < 4; mi++) {
            f32x4 sc[5];
#pragma unroll
            for (int q = 0; q < 5; q++) {
                sc[q] = acc[mi][0] * wA[q][0];
#pragma unroll
                for (int ni = 1; ni < 4; ni++) sc[q] += acc[mi][ni] * wA[q][ni];
            }
#pragma unroll
            for (int off = 1; off < 16; off <<= 1)
#pragma unroll
                for (int q = 0; q < 5; q++)
#pragma unroll
                    for (int c = 0; c < 4; c++)
                        sc[q][c] += __shfl_xor(sc[q][c], off);
            if (lr < 5) {
                const int q = lr;
                const int j0 = jb + mi * 16 + lh * 4;
                f32x4 v = sc[q] * 0.125f;
                *(f32x4*)&pglob[((size_t)(b5 * 8 + head) * 5 + q) * 1280 + t5 * 256 + j0] = v;
            }
        }
    } else {
        // va attention: per row, 5 scores vs ka, mask+scale, softmax5, @ va -> cat
        float wV[5][4];
#pragma unroll
        for (int q = 0; q < 5; q++)
#pragma unroll
            for (int ni = 0; ni < 4; ni++)
                wV[q][ni] = bf2f(aqkv[(size_t)(b5 * 5 + q) * 1536 + 1024 + head * 64 + ni * 16 + lr]);
#pragma unroll
        for (int mi = 0; mi < 4; mi++) {
            f32x4 sc[5];
#pragma unroll
            for (int q = 0; q < 5; q++) {
                sc[q] = acc[mi][0] * wA[q][0];
#pragma unroll
                for (int ni = 1; ni < 4; ni++) sc[q] += acc[mi][ni] * wA[q][ni];
            }
#pragma unroll
            for (int off = 1; off < 16; off <<= 1)
#pragma unroll
                for (int q = 0; q < 5; q++)
#pragma unroll
                    for (int c = 0; c < 4; c++)
                        sc[q][c] += __shfl_xor(sc[q][c], off);
            const int j0 = jb + mi * 16 + lh * 4;
            f32x4 mv;
#pragma unroll
            for (int c = 0; c < 4; c++) mv[c] = mask[bt * 256 + j0 + c] * 0.125f;
#pragma unroll
            for (int q = 0; q < 5; q++) sc[q] *= mv;
            f32x4 mx = sc[0];
#pragma unroll
            for (int q = 1; q < 5; q++)
#pragma unroll
                for (int c = 0; c < 4; c++) mx[c] = fmaxf(mx[c], sc[q][c]);
            f32x4 se = {};
#pragma unroll
            for (int q = 0; q < 5; q++) {
#pragma unroll
                for (int c = 0; c < 4; c++) sc[q][c] = __expf(sc[q][c] - mx[c]);
                se += sc[q];
            }
            f32x4 inv;
#pragma unroll
            for (int c = 0; c < 4; c++) inv[c] = 1.f / se[c];
#pragma unroll
            for (int ni = 0; ni < 4; ni++) {
                f32x4 o = sc[0] * wV[0][ni];
#pragma unroll
                for (int q = 1; q < 5; q++) o += sc[q] * wV[q][ni];
                o *= inv;
#pragma unroll
                for (int r2 = 0; r2 < 4; r2++) {
                    size_t g = (size_t)bt * 257 + 1 + j0 + r2;
                    cat[g * 512 + head * 64 + ni * 16 + lr] = f2bf(o[r2]);
                }
            }
        }
    }
}

// --- softmax in place over pglob rows. wave-per-row; grid 320 x 256 thr ---
__global__ __launch_bounds__(256) void av_softmax(float* __restrict__ pglob) {
    const int wave = threadIdx.x >> 6, lane = threadIdx.x & 63;
    const int rid = blockIdx.x * 4 + wave;
    float* row = pglob + (size_t)rid * 1280;
    float v[20];
    float mx = -3.4e38f;
#pragma unroll
    for (int i = 0; i < 20; i++) {
        v[i] = row[lane + i * 64];
        mx = fmaxf(mx, v[i]);
    }
#pragma unroll
    for (int off = 32; off > 0; off >>= 1) mx = fmaxf(mx, __shfl_xor(mx, off));
    float sum = 0.f;
#pragma unroll
    for (int i = 0; i < 20; i++) {
        v[i] = __expf(v[i] - mx);
        sum += v[i];
    }
#pragma unroll
    for (int off = 32; off > 0; off >>= 1) sum += __shfl_xor(sum, off);
    const float inv = 1.f / sum;
#pragma unroll
    for (int i = 0; i < 20; i++) row[lane + i * 64] = v[i] * inv;
}

// --- PV partials. grid 2048 = (bh)(256) x jc(8); 320 thr, wave=q, lane=d ---
__global__ __launch_bounds__(320) void av_pv(const u16* __restrict__ vv,
                                             const float* __restrict__ pglob,
                                             float* __restrict__ avpart) {
    __shared__ float pl[5][5][32];   // [q][t5][jj]
    const int blk = blockIdx.x;
    const int jc = blk & 7;
    const int bh = blk >> 3;
    const int bi = bh >> 3, hd = bh & 7;
    const int t = threadIdx.x;
    for (int ii = t; ii < 800; ii += 320) {
        int q = ii / 160, rem = ii - q * 160;
        int tt = rem >> 5, jj = rem & 31;
        pl[q][tt][jj] = pglob[((size_t)bh * 5 + q) * 1280 + tt * 256 + jc * 32 + jj];
    }
    __syncthreads();
    const int wave = t >> 6, lane = t & 63;   // wave = q
    float acc = 0.f;
    const int j0 = jc * 32;
    for (int jj = 0; jj < 32; jj++) {
#pragma unroll
        for (int t5 = 0; t5 < 5; t5++) {
            float v = bf2f(vv[((size_t)((bi * 5 + t5) * 256 + j0 + jj)) * 512 + hd * 64 + lane]);
            acc += pl[wave][t5][jj] * v;
        }
    }
    avpart[((size_t)jc * 1280 + (size_t)bh * 5 + wave) * 64 + lane] = acc;
}

// --- reduce partials -> cat A-rows. grid 320 x 256 thr ---
__global__ __launch_bounds__(256) void av_write(const float* __restrict__ avpart,
                                                u16* __restrict__ cat) {
    const int idx = blockIdx.x * 256 + threadIdx.x;
    const int d = idx & 63;
    const int r = idx >> 6;                   // 0..1279 = bh*5+q
    const int q = r % 5, bh = r / 5;
    const int bi = bh >> 3, hd = bh & 7;
    float s = 0.f;
#pragma unroll
    for (int jc = 0; jc < 8; jc++) s += avpart[((size_t)jc * 1280 + r) * 64 + d];
    cat[(size_t)((bi * 5 + q) * 257) * 512 + hd * 64 + d] = f2bf(s);
}

extern "C" void kernel_launch(void* const* d_in, const int* in_sizes, int n_in,
                              void* d_out, int out_size, void* d_ws, size_t ws_size,
                              hipStream_t stream) {
    const float* x    = (const float*)d_in[0];  // (160,257,512) f32
    const float* mask = (const float*)d_in[1];  // (160,256) f32
    const float* Wv   = (const float*)d_in[2];  // (512,1536) f32
    const float* Wa   = (const float*)d_in[3];  // (512,1536) f32
    const float* Wo   = (const float*)d_in[4];  // (512,512) f32
    const float* bo   = (const float*)d_in[5];  // (512,) f32
    float* out = (float*)d_out;

    char* ws = (char*)d_ws;
    u16*   xb     = (u16*)(ws);                   // 42,106,880 B
    u16*   WvT    = (u16*)(ws + 42106880);        //  1,572,864 B
    u16*   WaT    = (u16*)(ws + 43679744);        //  1,572,864 B
    u16*   WoT    = (u16*)(ws + 45252608);        //    524,288 B
    u16*   aqkv   = (u16*)(ws + 45776896);        //    491,520 B
    u16*   vv     = (u16*)(ws + 46268416);        // 41,943,040 B
    u16*   cat    = (u16*)(ws + 88211456);        // 42,106,880 B
    float* pglob  = (float*)(ws + 130318336);     //  6,553,600 B
    float* avpart = (float*)(ws + 136871936);     //  2,621,440 B -> ~139.5 MB

    prep<<<dim3(10728), 256, 0, stream>>>(x, Wv, Wa, Wo, xb, WvT, WaT, WoT);

    // a_qkv = A @ Wa_qkv (must precede gemm_qkv: its epilogues read aqkv)
    gemm_k<2, 0><<<dim3(12, 2), 256, 0, stream>>>(xb, WaT, aqkv, nullptr, 160, 1536, 512);

    // V-QKV GEMM with fused attention epilogues
    gemm_qkv<<<dim3(12, 320), 256, 0, stream>>>(xb, WvT, aqkv, mask, vv, pglob, cat);

    av_softmax<<<dim3(320), 256, 0, stream>>>(pglob);
    av_pv<<<dim3(2048), 320, 0, stream>>>(vv, pglob, avpart);
    av_write<<<dim3(320), 256, 0, stream>>>(avpart, cat);

    // out = cat @ Wo + bo   (float out)
    gemm_k<0, 1><<<dim3(4, 322), 256, 0, stream>>>(cat, WoT, out, bo, 41120, 512, 512);
}